// Round 18
// baseline (83.085 us; speedup 1.0000x reference)
//
#include <hip/hip_runtime.h>

#define NN 50000
#define NE 800000
#define NB 391            // dst buckets of 128 nodes (391*128 = 50048)
#define ECAP 3072         // per-bucket padded esrc16 capacity (max ~2300+pads)
#define SCAP 48           // per-(chunk,bucket) eord slot capacity (mean 10.5, +11 sigma)
#define CHUNK 4096        // edges per scat1 block
#define NCH ((NE + CHUNK - 1) / CHUNK)  // 196 chunks

typedef __attribute__((ext_vector_type(8))) short bf16x8;
typedef __attribute__((ext_vector_type(4))) float f32x4;
typedef __attribute__((ext_vector_type(2))) float f32x2;

__device__ __forceinline__ unsigned pack_bf16x2(float a, float b) {
    unsigned ua = __float_as_uint(a);
    unsigned ub = __float_as_uint(b);
    ua = (ua + 0x7FFFu + ((ua >> 16) & 1u)) >> 16;
    ub = (ub + 0x7FFFu + ((ub >> 16) & 1u)) >> 16;
    return ua | (ub << 16);
}
__device__ __forceinline__ unsigned pack_fp8x4(float a, float b, float c, float d) {
    int w = __builtin_amdgcn_cvt_pk_fp8_f32(a, b, 0, false);
    w = __builtin_amdgcn_cvt_pk_fp8_f32(c, d, w, true);
    return (unsigned)w;
}
__device__ __forceinline__ void dec8(unsigned lo, unsigned hi, float* a) {
    f32x2 p0 = __builtin_amdgcn_cvt_pk_f32_fp8(lo, false);
    f32x2 p1 = __builtin_amdgcn_cvt_pk_f32_fp8(lo, true);
    f32x2 p2 = __builtin_amdgcn_cvt_pk_f32_fp8(hi, false);
    f32x2 p3 = __builtin_amdgcn_cvt_pk_f32_fp8(hi, true);
    a[0] += p0.x; a[1] += p0.y; a[2] += p1.x; a[3] += p1.y;
    a[4] += p2.x; a[5] += p2.y; a[6] += p3.x; a[7] += p3.y;
}

// ---------------- pass 1 + prep: bucket-bin edges into fixed (chunk,bucket) slots ----------------
// blocks 0..NCH-1: binning. blocks NCH..NCH+11: W pack. block NCH+12: sentinel rows.
// packed edge: [31:16]=dst, [15:0]=src ; bucket = pk>>23
__global__ void k_scat1(const int* __restrict__ src, const int* __restrict__ dst,
                        int* __restrict__ pcnt, unsigned* __restrict__ eord,
                        const float* __restrict__ W1, const float* __restrict__ W2,
                        unsigned short* __restrict__ Wpk1, unsigned short* __restrict__ Wpk2,
                        unsigned* __restrict__ H1, unsigned* __restrict__ H2) {
    const int t = threadIdx.x;
    if (blockIdx.x >= NCH) {
        if (blockIdx.x == NCH + 12) {  // zero sentinel rows (node NN)
            if (t < 32) H1[(size_t)NN * 32 + t] = 0;
            else if (t < 48) H2[(size_t)NN * 16 + (t - 32)] = 0;
            return;
        }
        int gid = (blockIdx.x - NCH) * 256 + t;  // W-pack
        const float* W;
        unsigned short* Wpk;
        int idx, M;
        if (gid < 2048) { W = W1; Wpk = Wpk1; idx = gid; M = 128; }
        else if (gid < 3072) { W = W2; Wpk = Wpk2; idx = gid - 2048; M = 64; }
        else return;
        int l = idx & 63;
        int tt = (idx >> 6) & 3;
        int ct = idx >> 8;
        int col = ct * 16 + (l & 15);
        int k0 = tt * 32 + (l >> 4) * 8;
        unsigned* o = (unsigned*)(Wpk + (size_t)idx * 8);
#pragma unroll
        for (int j = 0; j < 8; j += 2)
            o[j >> 1] = pack_bf16x2(W[(size_t)(k0 + j) * M + col], W[(size_t)(k0 + j + 1) * M + col]);
        return;
    }
    __shared__ int hist[NB];
    const int e0 = blockIdx.x * CHUNK;
    for (int j = t; j < NB; j += 256) hist[j] = 0;
    __syncthreads();
    unsigned pk[16];
#pragma unroll
    for (int i = 0; i < 16; ++i) {
        int e = e0 + t + i * 256;
        pk[i] = 0xFFFFFFFFu;
        if (e < NE) {
            unsigned s = (unsigned)src[e];
            unsigned d = (unsigned)dst[e];
            pk[i] = (d << 16) | s;
            atomicAdd(&hist[d >> 7], 1);
        }
    }
    __syncthreads();
    for (int j = t; j < NB; j += 256) {
        pcnt[(size_t)j * NCH + blockIdx.x] = hist[j];
        hist[j] = 0;  // reuse as within-block cursor
    }
    __syncthreads();
#pragma unroll
    for (int i = 0; i < 16; ++i) {
        if (pk[i] != 0xFFFFFFFFu) {
            int bk = pk[i] >> 23;
            int pos = (bk * NCH + blockIdx.x) * SCAP + atomicAdd(&hist[bk], 1);
            eord[pos] = pk[i];
        }
    }
}

// ---------------- pass 2 + GEMM1: within-bucket sort -> esrc16/rs2/dinv, then MFMA for 128 rows ----------------
__global__ __launch_bounds__(256) void k_scat2g1(const int* __restrict__ pcnt,
                                                 const unsigned* __restrict__ eord,
                                                 unsigned short* __restrict__ esrc16,
                                                 uint2* __restrict__ rs2, float* __restrict__ dinv,
                                                 const float* __restrict__ X,
                                                 const unsigned short* __restrict__ Wpk,
                                                 unsigned* __restrict__ H1) {
    __shared__ int sp[NCH + 1];   // segment exclusive prefix (197 ints)
    __shared__ int tmp[256];
    __shared__ int cnt[128];
    __shared__ int pre[128];
    __shared__ int cur[128];
    __shared__ float sdv[128];
    const int b = blockIdx.x, t = threadIdx.x, d0 = b << 7;
    const int base = b * ECAP;
    // segment counts -> prefix (NCH=196 entries via 256-thread scan)
    int c = (t < NCH) ? pcnt[(size_t)b * NCH + t] : 0;
    tmp[t] = c;
    if (t < 128) cnt[t] = 0;
    __syncthreads();
    for (int o = 1; o < 256; o <<= 1) {
        int a = (t >= o) ? tmp[t - o] : 0;
        __syncthreads();
        tmp[t] += a;
        __syncthreads();
    }
    if (t < NCH) sp[t + 1] = tmp[t];
    if (t == 0) sp[0] = 0;
    __syncthreads();
    const int nE = sp[NCH];
    // gather edges (binary search segment), histogram by dst&127
    unsigned pk[12];
#pragma unroll
    for (int it = 0; it < 12; ++it) {
        int i = t + it * 256;
        if (i < nE) {
            int lo = 0, hi = NCH - 1;
            while (lo < hi) {
                int mid = (lo + hi + 1) >> 1;
                if (sp[mid] <= i) lo = mid; else hi = mid - 1;
            }
            pk[it] = eord[((size_t)b * NCH + lo) * SCAP + (i - sp[lo])];
            atomicAdd(&cnt[(pk[it] >> 16) & 127], 1);
        }
    }
    __syncthreads();
    int v = (t < 128) ? cnt[t] : 0;
    int pc = (v + 3) & ~3;  // pad to multiple of 4
    if (t < 128) pre[t] = pc;
    __syncthreads();
    for (int o = 1; o < 128; o <<= 1) {
        int a = (t < 128 && t >= o) ? pre[t - o] : 0;
        __syncthreads();
        if (t < 128) pre[t] += a;
        __syncthreads();
    }
    if (t < 128) {
        int st = base + pre[t] - pc;
        int d = d0 + t;
        float dv = rsqrtf((float)(v + 1));  // +1 self-loop
        sdv[t] = dv;
        if (d < NN) {
            rs2[d] = make_uint2((unsigned)st, (unsigned)pc);
            dinv[d] = dv;
        }
        cur[t] = st;
        for (int k = v; k < pc; ++k) esrc16[st + k] = (unsigned short)NN;  // sentinel pads
    }
    __syncthreads();
#pragma unroll
    for (int it = 0; it < 12; ++it) {
        int i = t + it * 256;
        if (i < nE) {
            int pos = atomicAdd(&cur[(pk[it] >> 16) & 127], 1);
            esrc16[pos] = (unsigned short)(pk[it] & 0xFFFFu);
        }
    }
    __syncthreads();
    // ---- GEMM1 for this bucket's 128 rows: 2 passes of 64 (4 waves x 16 rows) ----
    const int w = t >> 6, l = t & 63;
    const int lq = l >> 4;
    for (int pass = 0; pass < 2; ++pass) {
        const int lrow = pass * 64 + w * 16 + (l & 15);
        const int row = d0 + lrow;
        const int rc = row < NN ? row : NN - 1;
        f32x4 acc[8];
#pragma unroll
        for (int cc = 0; cc < 8; ++cc) acc[cc] = (f32x4){0.f, 0.f, 0.f, 0.f};
#pragma unroll
        for (int tt = 0; tt < 4; ++tt) {
            const float4* xp = (const float4*)(X + (size_t)rc * 128 + tt * 32 + lq * 8);
            float4 xa = xp[0], xb = xp[1];
            bf16x8 xf;
            unsigned* xu = (unsigned*)&xf;
            xu[0] = pack_bf16x2(xa.x, xa.y);
            xu[1] = pack_bf16x2(xa.z, xa.w);
            xu[2] = pack_bf16x2(xb.x, xb.y);
            xu[3] = pack_bf16x2(xb.z, xb.w);
#pragma unroll
            for (int cc = 0; cc < 8; ++cc) {
                bf16x8 wf = *(const bf16x8*)(Wpk + (size_t)((cc * 4 + tt) * 64 + l) * 8);
                acc[cc] = __builtin_amdgcn_mfma_f32_16x16x32_bf16(wf, xf, acc[cc], 0, 0, 0);
            }
        }
        if (row < NN) {
            float s = sdv[lrow];
            unsigned* orow = H1 + (size_t)row * 32;
#pragma unroll
            for (int cc = 0; cc < 8; ++cc)
                orow[cc * 4 + lq] = pack_fp8x4(acc[cc][0] * s, acc[cc][1] * s,
                                               acc[cc][2] * s, acc[cc][3] * s);
        }
    }
}

// ---------------- FUSED layer-1 aggregate + GEMM2 ----------------
__global__ __launch_bounds__(256) void k_agg1g2(const uint2* __restrict__ rs2,
                                                const unsigned short* __restrict__ esrc,
                                                const unsigned* __restrict__ H1,
                                                const float* __restrict__ dinv,
                                                const float* __restrict__ b1,
                                                const unsigned short* __restrict__ Wpk2,
                                                unsigned* __restrict__ H2) {
    __shared__ unsigned x2[32][68];  // 32 nodes x 128 bf16, stride 68 u32 -> 2-way-free banks
    const int t = threadIdx.x;
    const int w = t >> 6, lane = t & 63;
    const int g = lane >> 3, gl = lane & 7;
    const int nbase = blockIdx.x * 32;
    const int wid = nbase + w * 8 + g;
    float a[16];
#pragma unroll
    for (int k = 0; k < 16; ++k) a[k] = 0.f;
    if (wid < NN) {
        uint2 r = rs2[wid];
        const unsigned short* ep = esrc + r.x;
        int n4 = (int)r.y;
        const uint4* Hp = (const uint4*)H1;  // row = 8 uint4
        for (int j = 0; j < n4; j += 4) {
            unsigned long long i4 = *(const unsigned long long*)(ep + j);
            int s0 = (int)(i4 & 0xFFFF), s1 = (int)((i4 >> 16) & 0xFFFF);
            int s2 = (int)((i4 >> 32) & 0xFFFF), s3 = (int)(i4 >> 48);
            uint4 v0 = Hp[(size_t)s0 * 8 + gl];
            uint4 v1 = Hp[(size_t)s1 * 8 + gl];
            uint4 v2 = Hp[(size_t)s2 * 8 + gl];
            uint4 v3 = Hp[(size_t)s3 * 8 + gl];
            dec8(v0.x, v0.y, a); dec8(v0.z, v0.w, a + 8);
            dec8(v1.x, v1.y, a); dec8(v1.z, v1.w, a + 8);
            dec8(v2.x, v2.y, a); dec8(v2.z, v2.w, a + 8);
            dec8(v3.x, v3.y, a); dec8(v3.z, v3.w, a + 8);
        }
        {   // self-loop
            uint4 v = Hp[(size_t)wid * 8 + gl];
            dec8(v.x, v.y, a); dec8(v.z, v.w, a + 8);
        }
        float di = dinv[wid];
        const float4* bp = (const float4*)b1;
#pragma unroll
        for (int kq = 0; kq < 4; ++kq) {
            float4 bv = bp[gl * 4 + kq];
            a[kq * 4 + 0] = fmaxf(fmaf(di, a[kq * 4 + 0], bv.x), 0.f);
            a[kq * 4 + 1] = fmaxf(fmaf(di, a[kq * 4 + 1], bv.y), 0.f);
            a[kq * 4 + 2] = fmaxf(fmaf(di, a[kq * 4 + 2], bv.z), 0.f);
            a[kq * 4 + 3] = fmaxf(fmaf(di, a[kq * 4 + 3], bv.w), 0.f);
        }
    }
    {   // stage X2 row (bf16) to LDS
        const int nl = w * 8 + g;
        unsigned* row = &x2[nl][gl * 8];
        row[0] = pack_bf16x2(a[0], a[1]);
        row[1] = pack_bf16x2(a[2], a[3]);
        row[2] = pack_bf16x2(a[4], a[5]);
        row[3] = pack_bf16x2(a[6], a[7]);
        row[4] = pack_bf16x2(a[8], a[9]);
        row[5] = pack_bf16x2(a[10], a[11]);
        row[6] = pack_bf16x2(a[12], a[13]);
        row[7] = pack_bf16x2(a[14], a[15]);
    }
    __syncthreads();
    // ---- phase B: wave w -> rows (w&1)*16..+15, col-tiles (w>>1)*2..+1 ----
    const int lrow = (w & 1) * 16 + (lane & 15);
    const int lq = lane >> 4;
    const int c0 = (w >> 1) * 2;
    f32x4 acc0 = (f32x4){0.f, 0.f, 0.f, 0.f};
    f32x4 acc1 = (f32x4){0.f, 0.f, 0.f, 0.f};
#pragma unroll
    for (int tt = 0; tt < 4; ++tt) {
        bf16x8 xf = *(const bf16x8*)&x2[lrow][tt * 16 + lq * 4];
        bf16x8 wf0 = *(const bf16x8*)(Wpk2 + (size_t)((c0 * 4 + tt) * 64 + lane) * 8);
        bf16x8 wf1 = *(const bf16x8*)(Wpk2 + (size_t)(((c0 + 1) * 4 + tt) * 64 + lane) * 8);
        acc0 = __builtin_amdgcn_mfma_f32_16x16x32_bf16(wf0, xf, acc0, 0, 0, 0);
        acc1 = __builtin_amdgcn_mfma_f32_16x16x32_bf16(wf1, xf, acc1, 0, 0, 0);
    }
    const int orow_i = nbase + lrow;
    if (orow_i < NN) {
        float s = dinv[orow_i];
        unsigned* orow = H2 + (size_t)orow_i * 16;
        orow[c0 * 4 + lq] = pack_fp8x4(acc0[0] * s, acc0[1] * s, acc0[2] * s, acc0[3] * s);
        orow[(c0 + 1) * 4 + lq] = pack_fp8x4(acc1[0] * s, acc1[1] * s, acc1[2] * s, acc1[3] * s);
    }
}

// ---------------- layer-2 aggregate + log_softmax: 4-lane group per node, uint4/lane ----------------
__global__ void k_agg2_lsm(const uint2* __restrict__ rs2, const unsigned short* __restrict__ esrc,
                           const unsigned* __restrict__ H2, const float* __restrict__ dinv,
                           const float* __restrict__ b, float* __restrict__ OUT) {
    int wave = (blockIdx.x * blockDim.x + threadIdx.x) >> 6;
    int lane = threadIdx.x & 63;
    int g = lane >> 2, gl = lane & 3;
    int wid = wave * 16 + g;
    if (wid >= NN) return;
    uint2 r = rs2[wid];
    const unsigned short* ep = esrc + r.x;
    int n4 = (int)r.y;
    const uint4* Hp = (const uint4*)H2;  // row = 4 uint4
    float a[16];
#pragma unroll
    for (int k = 0; k < 16; ++k) a[k] = 0.f;
    for (int j = 0; j < n4; j += 4) {
        unsigned long long i4 = *(const unsigned long long*)(ep + j);
        int s0 = (int)(i4 & 0xFFFF), s1 = (int)((i4 >> 16) & 0xFFFF);
        int s2 = (int)((i4 >> 32) & 0xFFFF), s3 = (int)(i4 >> 48);
        uint4 v0 = Hp[(size_t)s0 * 4 + gl];
        uint4 v1 = Hp[(size_t)s1 * 4 + gl];
        uint4 v2 = Hp[(size_t)s2 * 4 + gl];
        uint4 v3 = Hp[(size_t)s3 * 4 + gl];
        dec8(v0.x, v0.y, a); dec8(v0.z, v0.w, a + 8);
        dec8(v1.x, v1.y, a); dec8(v1.z, v1.w, a + 8);
        dec8(v2.x, v2.y, a); dec8(v2.z, v2.w, a + 8);
        dec8(v3.x, v3.y, a); dec8(v3.z, v3.w, a + 8);
    }
    {   // self-loop
        uint4 v = Hp[(size_t)wid * 4 + gl];
        dec8(v.x, v.y, a); dec8(v.z, v.w, a + 8);
    }
    float di = dinv[wid];
    float v[16];
    const float4* bp = (const float4*)b;
#pragma unroll
    for (int kq = 0; kq < 4; ++kq) {
        float4 bv = bp[gl * 4 + kq];
        v[kq * 4 + 0] = fmaf(di, a[kq * 4 + 0], bv.x);
        v[kq * 4 + 1] = fmaf(di, a[kq * 4 + 1], bv.y);
        v[kq * 4 + 2] = fmaf(di, a[kq * 4 + 2], bv.z);
        v[kq * 4 + 3] = fmaf(di, a[kq * 4 + 3], bv.w);
    }
    float m = v[0];
#pragma unroll
    for (int k = 1; k < 16; ++k) m = fmaxf(m, v[k]);
    m = fmaxf(m, __shfl_xor(m, 1));
    m = fmaxf(m, __shfl_xor(m, 2));
    float s = 0.f;
#pragma unroll
    for (int k = 0; k < 16; ++k) s += expf(v[k] - m);
    s += __shfl_xor(s, 1);
    s += __shfl_xor(s, 2);
    float ls = m + logf(s);
#pragma unroll
    for (int kq = 0; kq < 4; ++kq) {
        float4 o4;
        o4.x = v[kq * 4 + 0] - ls;
        o4.y = v[kq * 4 + 1] - ls;
        o4.z = v[kq * 4 + 2] - ls;
        o4.w = v[kq * 4 + 3] - ls;
        ((float4*)OUT)[(size_t)wid * 16 + gl * 4 + kq] = o4;
    }
}

extern "C" void kernel_launch(void* const* d_in, const int* in_sizes, int n_in,
                              void* d_out, int out_size, void* d_ws, size_t ws_size,
                              hipStream_t stream) {
    const float* x = (const float*)d_in[0];
    const int* ei = (const int*)d_in[1];  // [2, NE] int32
    const float* W1 = (const float*)d_in[2];
    const float* b1 = (const float*)d_in[3];
    const float* W2 = (const float*)d_in[4];
    const float* b2 = (const float*)d_in[5];
    float* out = (float*)d_out;

    const int* src = ei;
    const int* dst = ei + NE;

    // workspace layout (all segments 16B-aligned)
    int* pcnt = (int*)d_ws;                                  // NB*NCH ints (306KB)
    uint2* rs2 = (uint2*)(pcnt + NB * NCH + 2);              // NN uint2
    float* dinv = (float*)(rs2 + NN);                        // NN
    unsigned short* Wpk1 = (unsigned short*)(dinv + NN);     // 2048*8 bf16 (32KB)
    unsigned short* Wpk2 = Wpk1 + 2048 * 8;                  // 1024*8 bf16 (16KB)
    unsigned* eord = (unsigned*)(Wpk2 + 1024 * 8);           // NB*NCH*SCAP u32 (14.7MB)
    unsigned short* esrc16 = (unsigned short*)(eord + (size_t)NB * NCH * SCAP);  // NB*ECAP u16
    unsigned* H1f8 = (unsigned*)(esrc16 + (size_t)NB * ECAP);  // (NN+1)*32 u32 (fp8, +sentinel)
    unsigned* H2f8 = H1f8 + (size_t)(NN + 1) * 32;           // (NN+1)*16 u32 (fp8, +sentinel)

    k_scat1<<<NCH + 13, 256, 0, stream>>>(src, dst, pcnt, eord, W1, W2, Wpk1, Wpk2, H1f8, H2f8);
    k_scat2g1<<<NB, 256, 0, stream>>>(pcnt, eord, esrc16, rs2, dinv, x, Wpk1, H1f8);
    k_agg1g2<<<(NN + 31) / 32, 256, 0, stream>>>(rs2, esrc16, H1f8, dinv, b1, Wpk2, H2f8);
    k_agg2_lsm<<<(((NN + 15) / 16) * 64 + 255) / 256, 256, 0, stream>>>(rs2, esrc16, H2f8,
                                                                        dinv, b2, out);
}

// Round 19
// 82.013 us; speedup vs baseline: 1.0131x; 1.0131x over previous
//
#include <hip/hip_runtime.h>

#define NN 50000
#define NE 800000
#define NB 391            // dst buckets of 128 nodes (391*128 = 50048)
#define ECAP 3072         // per-bucket padded esrc16 capacity (max ~2300+pads)
#define SCAP 80           // per-(chunk,bucket) eord slot capacity (mean 21, +13 sigma)
#define CHUNK 8192        // edges per scat1 block
#define NCH ((NE + CHUNK - 1) / CHUNK)  // 98 chunks

typedef __attribute__((ext_vector_type(8))) short bf16x8;
typedef __attribute__((ext_vector_type(4))) float f32x4;
typedef __attribute__((ext_vector_type(2))) float f32x2;

__device__ __forceinline__ unsigned pack_bf16x2(float a, float b) {
    unsigned ua = __float_as_uint(a);
    unsigned ub = __float_as_uint(b);
    ua = (ua + 0x7FFFu + ((ua >> 16) & 1u)) >> 16;
    ub = (ub + 0x7FFFu + ((ub >> 16) & 1u)) >> 16;
    return ua | (ub << 16);
}
__device__ __forceinline__ unsigned pack_fp8x4(float a, float b, float c, float d) {
    int w = __builtin_amdgcn_cvt_pk_fp8_f32(a, b, 0, false);
    w = __builtin_amdgcn_cvt_pk_fp8_f32(c, d, w, true);
    return (unsigned)w;
}
// decode 8 fp8 (two u32) into 4 packed f32x2 accumulators (v_pk_add_f32)
__device__ __forceinline__ void dec8v(unsigned lo, unsigned hi, f32x2* a) {
    a[0] += __builtin_amdgcn_cvt_pk_f32_fp8(lo, false);
    a[1] += __builtin_amdgcn_cvt_pk_f32_fp8(lo, true);
    a[2] += __builtin_amdgcn_cvt_pk_f32_fp8(hi, false);
    a[3] += __builtin_amdgcn_cvt_pk_f32_fp8(hi, true);
}

// ---------------- pass 1 + prep: bucket-bin edges into fixed (chunk,bucket) slots ----------------
// blocks 0..NCH-1: binning. blocks NCH..NCH+11: W pack. block NCH+12: sentinel rows.
// packed edge: [31:16]=dst, [15:0]=src ; bucket = pk>>23
__global__ void k_scat1(const int* __restrict__ src, const int* __restrict__ dst,
                        int* __restrict__ pcnt, unsigned* __restrict__ eord,
                        const float* __restrict__ W1, const float* __restrict__ W2,
                        unsigned short* __restrict__ Wpk1, unsigned short* __restrict__ Wpk2,
                        unsigned* __restrict__ H1, unsigned* __restrict__ H2) {
    const int t = threadIdx.x;
    if (blockIdx.x >= NCH) {
        if (blockIdx.x == NCH + 12) {  // zero sentinel rows (node NN)
            if (t < 32) H1[(size_t)NN * 32 + t] = 0;
            else if (t < 48) H2[(size_t)NN * 16 + (t - 32)] = 0;
            return;
        }
        int gid = (blockIdx.x - NCH) * 256 + t;  // W-pack
        const float* W;
        unsigned short* Wpk;
        int idx, M;
        if (gid < 2048) { W = W1; Wpk = Wpk1; idx = gid; M = 128; }
        else if (gid < 3072) { W = W2; Wpk = Wpk2; idx = gid - 2048; M = 64; }
        else return;
        int l = idx & 63;
        int tt = (idx >> 6) & 3;
        int ct = idx >> 8;
        int col = ct * 16 + (l & 15);
        int k0 = tt * 32 + (l >> 4) * 8;
        unsigned* o = (unsigned*)(Wpk + (size_t)idx * 8);
#pragma unroll
        for (int j = 0; j < 8; j += 2)
            o[j >> 1] = pack_bf16x2(W[(size_t)(k0 + j) * M + col], W[(size_t)(k0 + j + 1) * M + col]);
        return;
    }
    __shared__ int hist[NB];
    const int e0 = blockIdx.x * CHUNK;
    for (int j = t; j < NB; j += 256) hist[j] = 0;
    __syncthreads();
    unsigned pk[32];
#pragma unroll
    for (int i = 0; i < 32; ++i) {
        int e = e0 + t + i * 256;
        pk[i] = 0xFFFFFFFFu;
        if (e < NE) {
            unsigned s = (unsigned)src[e];
            unsigned d = (unsigned)dst[e];
            pk[i] = (d << 16) | s;
            atomicAdd(&hist[d >> 7], 1);
        }
    }
    __syncthreads();
    for (int j = t; j < NB; j += 256) {
        pcnt[(size_t)j * NCH + blockIdx.x] = hist[j];
        hist[j] = 0;  // reuse as within-block cursor
    }
    __syncthreads();
#pragma unroll
    for (int i = 0; i < 32; ++i) {
        if (pk[i] != 0xFFFFFFFFu) {
            int bk = pk[i] >> 23;
            int pos = (bk * NCH + blockIdx.x) * SCAP + atomicAdd(&hist[bk], 1);
            eord[pos] = pk[i];
        }
    }
}

// ---------------- pass 2 + GEMM1: within-bucket sort -> esrc16/rs2/dinv, then MFMA for 128 rows ----------------
__global__ __launch_bounds__(256) void k_scat2g1(const int* __restrict__ pcnt,
                                                 const unsigned* __restrict__ eord,
                                                 unsigned short* __restrict__ esrc16,
                                                 uint2* __restrict__ rs2, float* __restrict__ dinv,
                                                 const float* __restrict__ X,
                                                 const unsigned short* __restrict__ Wpk,
                                                 unsigned* __restrict__ H1) {
    __shared__ int sp[NCH + 1];   // segment exclusive prefix
    __shared__ int tmp[128];
    __shared__ int cnt[128];
    __shared__ int pre[128];
    __shared__ int cur[128];
    __shared__ float sdv[128];
    const int b = blockIdx.x, t = threadIdx.x, d0 = b << 7;
    const int base = b * ECAP;
    // segment counts -> prefix (98 entries via 128-thread scan)
    int c = 0;
    if (t < NCH) c = pcnt[(size_t)b * NCH + t];
    if (t < 128) tmp[t] = (t < NCH) ? c : 0;
    if (t < 128) cnt[t] = 0;
    __syncthreads();
    for (int o = 1; o < 128; o <<= 1) {
        int a = (t < 128 && t >= o) ? tmp[t - o] : 0;
        __syncthreads();
        if (t < 128) tmp[t] += a;
        __syncthreads();
    }
    if (t < NCH) sp[t + 1] = tmp[t];
    if (t == 0) sp[0] = 0;
    __syncthreads();
    const int nE = sp[NCH];
    // gather edges (binary search segment), histogram by dst&127
    unsigned pk[12];
#pragma unroll
    for (int it = 0; it < 12; ++it) {
        int i = t + it * 256;
        if (i < nE) {
            int lo = 0, hi = NCH - 1;
            while (lo < hi) {
                int mid = (lo + hi + 1) >> 1;
                if (sp[mid] <= i) lo = mid; else hi = mid - 1;
            }
            pk[it] = eord[((size_t)b * NCH + lo) * SCAP + (i - sp[lo])];
            atomicAdd(&cnt[(pk[it] >> 16) & 127], 1);
        }
    }
    __syncthreads();
    int v = (t < 128) ? cnt[t] : 0;
    int pc = (v + 3) & ~3;  // pad to multiple of 4
    if (t < 128) pre[t] = pc;
    __syncthreads();
    for (int o = 1; o < 128; o <<= 1) {
        int a = (t < 128 && t >= o) ? pre[t - o] : 0;
        __syncthreads();
        if (t < 128) pre[t] += a;
        __syncthreads();
    }
    if (t < 128) {
        int st = base + pre[t] - pc;
        int d = d0 + t;
        float dv = rsqrtf((float)(v + 1));  // +1 self-loop
        sdv[t] = dv;
        if (d < NN) {
            rs2[d] = make_uint2((unsigned)st, (unsigned)pc);
            dinv[d] = dv;
        }
        cur[t] = st;
        for (int k = v; k < pc; ++k) esrc16[st + k] = (unsigned short)NN;  // sentinel pads
    }
    __syncthreads();
#pragma unroll
    for (int it = 0; it < 12; ++it) {
        int i = t + it * 256;
        if (i < nE) {
            int pos = atomicAdd(&cur[(pk[it] >> 16) & 127], 1);
            esrc16[pos] = (unsigned short)(pk[it] & 0xFFFFu);
        }
    }
    __syncthreads();
    // ---- GEMM1 for this bucket's 128 rows: 2 passes of 64 (4 waves x 16 rows) ----
    const int w = t >> 6, l = t & 63;
    const int lq = l >> 4;
    for (int pass = 0; pass < 2; ++pass) {
        const int lrow = pass * 64 + w * 16 + (l & 15);
        const int row = d0 + lrow;
        const int rc = row < NN ? row : NN - 1;
        f32x4 acc[8];
#pragma unroll
        for (int cc = 0; cc < 8; ++cc) acc[cc] = (f32x4){0.f, 0.f, 0.f, 0.f};
#pragma unroll
        for (int tt = 0; tt < 4; ++tt) {
            const float4* xp = (const float4*)(X + (size_t)rc * 128 + tt * 32 + lq * 8);
            float4 xa = xp[0], xb = xp[1];
            bf16x8 xf;
            unsigned* xu = (unsigned*)&xf;
            xu[0] = pack_bf16x2(xa.x, xa.y);
            xu[1] = pack_bf16x2(xa.z, xa.w);
            xu[2] = pack_bf16x2(xb.x, xb.y);
            xu[3] = pack_bf16x2(xb.z, xb.w);
#pragma unroll
            for (int cc = 0; cc < 8; ++cc) {
                bf16x8 wf = *(const bf16x8*)(Wpk + (size_t)((cc * 4 + tt) * 64 + l) * 8);
                acc[cc] = __builtin_amdgcn_mfma_f32_16x16x32_bf16(wf, xf, acc[cc], 0, 0, 0);
            }
        }
        if (row < NN) {
            float s = sdv[lrow];
            unsigned* orow = H1 + (size_t)row * 32;
#pragma unroll
            for (int cc = 0; cc < 8; ++cc)
                orow[cc * 4 + lq] = pack_fp8x4(acc[cc][0] * s, acc[cc][1] * s,
                                               acc[cc][2] * s, acc[cc][3] * s);
        }
    }
}

// ---------------- FUSED layer-1 aggregate + GEMM2 (packed f32x2 accumulators) ----------------
__global__ __launch_bounds__(256) void k_agg1g2(const uint2* __restrict__ rs2,
                                                const unsigned short* __restrict__ esrc,
                                                const unsigned* __restrict__ H1,
                                                const float* __restrict__ dinv,
                                                const float* __restrict__ b1,
                                                const unsigned short* __restrict__ Wpk2,
                                                unsigned* __restrict__ H2) {
    __shared__ unsigned x2[32][68];  // 32 nodes x 128 bf16, stride 68 u32 -> 2-way-free banks
    const int t = threadIdx.x;
    const int w = t >> 6, lane = t & 63;
    const int g = lane >> 3, gl = lane & 7;
    const int nbase = blockIdx.x * 32;
    const int wid = nbase + w * 8 + g;
    f32x2 av[8];
#pragma unroll
    for (int k = 0; k < 8; ++k) av[k] = (f32x2){0.f, 0.f};
    if (wid < NN) {
        uint2 r = rs2[wid];
        const unsigned short* ep = esrc + r.x;
        int n4 = (int)r.y;
        const uint4* Hp = (const uint4*)H1;  // row = 8 uint4
        for (int j = 0; j < n4; j += 4) {
            unsigned long long i4 = *(const unsigned long long*)(ep + j);
            int s0 = (int)(i4 & 0xFFFF), s1 = (int)((i4 >> 16) & 0xFFFF);
            int s2 = (int)((i4 >> 32) & 0xFFFF), s3 = (int)(i4 >> 48);
            uint4 v0 = Hp[(size_t)s0 * 8 + gl];
            uint4 v1 = Hp[(size_t)s1 * 8 + gl];
            uint4 v2 = Hp[(size_t)s2 * 8 + gl];
            uint4 v3 = Hp[(size_t)s3 * 8 + gl];
            dec8v(v0.x, v0.y, av); dec8v(v0.z, v0.w, av + 4);
            dec8v(v1.x, v1.y, av); dec8v(v1.z, v1.w, av + 4);
            dec8v(v2.x, v2.y, av); dec8v(v2.z, v2.w, av + 4);
            dec8v(v3.x, v3.y, av); dec8v(v3.z, v3.w, av + 4);
        }
        {   // self-loop
            uint4 v = Hp[(size_t)wid * 8 + gl];
            dec8v(v.x, v.y, av); dec8v(v.z, v.w, av + 4);
        }
    }
    float a[16];
#pragma unroll
    for (int k = 0; k < 8; ++k) { a[2 * k] = av[k][0]; a[2 * k + 1] = av[k][1]; }
    if (wid < NN) {
        float di = dinv[wid];
        const float4* bp = (const float4*)b1;
#pragma unroll
        for (int kq = 0; kq < 4; ++kq) {
            float4 bv = bp[gl * 4 + kq];
            a[kq * 4 + 0] = fmaxf(fmaf(di, a[kq * 4 + 0], bv.x), 0.f);
            a[kq * 4 + 1] = fmaxf(fmaf(di, a[kq * 4 + 1], bv.y), 0.f);
            a[kq * 4 + 2] = fmaxf(fmaf(di, a[kq * 4 + 2], bv.z), 0.f);
            a[kq * 4 + 3] = fmaxf(fmaf(di, a[kq * 4 + 3], bv.w), 0.f);
        }
    } else {
#pragma unroll
        for (int k = 0; k < 16; ++k) a[k] = 0.f;
    }
    {   // stage X2 row (bf16) to LDS
        const int nl = w * 8 + g;
        unsigned* row = &x2[nl][gl * 8];
        row[0] = pack_bf16x2(a[0], a[1]);
        row[1] = pack_bf16x2(a[2], a[3]);
        row[2] = pack_bf16x2(a[4], a[5]);
        row[3] = pack_bf16x2(a[6], a[7]);
        row[4] = pack_bf16x2(a[8], a[9]);
        row[5] = pack_bf16x2(a[10], a[11]);
        row[6] = pack_bf16x2(a[12], a[13]);
        row[7] = pack_bf16x2(a[14], a[15]);
    }
    __syncthreads();
    // ---- phase B: wave w -> rows (w&1)*16..+15, col-tiles (w>>1)*2..+1 ----
    const int lrow = (w & 1) * 16 + (lane & 15);
    const int lq = lane >> 4;
    const int c0 = (w >> 1) * 2;
    f32x4 acc0 = (f32x4){0.f, 0.f, 0.f, 0.f};
    f32x4 acc1 = (f32x4){0.f, 0.f, 0.f, 0.f};
#pragma unroll
    for (int tt = 0; tt < 4; ++tt) {
        bf16x8 xf = *(const bf16x8*)&x2[lrow][tt * 16 + lq * 4];
        bf16x8 wf0 = *(const bf16x8*)(Wpk2 + (size_t)((c0 * 4 + tt) * 64 + lane) * 8);
        bf16x8 wf1 = *(const bf16x8*)(Wpk2 + (size_t)(((c0 + 1) * 4 + tt) * 64 + lane) * 8);
        acc0 = __builtin_amdgcn_mfma_f32_16x16x32_bf16(wf0, xf, acc0, 0, 0, 0);
        acc1 = __builtin_amdgcn_mfma_f32_16x16x32_bf16(wf1, xf, acc1, 0, 0, 0);
    }
    const int orow_i = nbase + lrow;
    if (orow_i < NN) {
        float s = dinv[orow_i];
        unsigned* orow = H2 + (size_t)orow_i * 16;
        orow[c0 * 4 + lq] = pack_fp8x4(acc0[0] * s, acc0[1] * s, acc0[2] * s, acc0[3] * s);
        orow[(c0 + 1) * 4 + lq] = pack_fp8x4(acc1[0] * s, acc1[1] * s, acc1[2] * s, acc1[3] * s);
    }
}

// ---------------- layer-2 aggregate + log_softmax: 4-lane groups, packed accumulators ----------------
__global__ void k_agg2_lsm(const uint2* __restrict__ rs2, const unsigned short* __restrict__ esrc,
                           const unsigned* __restrict__ H2, const float* __restrict__ dinv,
                           const float* __restrict__ b, float* __restrict__ OUT) {
    int wave = (blockIdx.x * blockDim.x + threadIdx.x) >> 6;
    int lane = threadIdx.x & 63;
    int g = lane >> 2, gl = lane & 3;
    int wid = wave * 16 + g;
    if (wid >= NN) return;
    uint2 r = rs2[wid];
    const unsigned short* ep = esrc + r.x;
    int n4 = (int)r.y;
    const uint4* Hp = (const uint4*)H2;  // row = 4 uint4
    f32x2 av[8];
#pragma unroll
    for (int k = 0; k < 8; ++k) av[k] = (f32x2){0.f, 0.f};
    for (int j = 0; j < n4; j += 4) {
        unsigned long long i4 = *(const unsigned long long*)(ep + j);
        int s0 = (int)(i4 & 0xFFFF), s1 = (int)((i4 >> 16) & 0xFFFF);
        int s2 = (int)((i4 >> 32) & 0xFFFF), s3 = (int)(i4 >> 48);
        uint4 v0 = Hp[(size_t)s0 * 4 + gl];
        uint4 v1 = Hp[(size_t)s1 * 4 + gl];
        uint4 v2 = Hp[(size_t)s2 * 4 + gl];
        uint4 v3 = Hp[(size_t)s3 * 4 + gl];
        dec8v(v0.x, v0.y, av); dec8v(v0.z, v0.w, av + 4);
        dec8v(v1.x, v1.y, av); dec8v(v1.z, v1.w, av + 4);
        dec8v(v2.x, v2.y, av); dec8v(v2.z, v2.w, av + 4);
        dec8v(v3.x, v3.y, av); dec8v(v3.z, v3.w, av + 4);
    }
    {   // self-loop
        uint4 v = Hp[(size_t)wid * 4 + gl];
        dec8v(v.x, v.y, av); dec8v(v.z, v.w, av + 4);
    }
    float a[16];
#pragma unroll
    for (int k = 0; k < 8; ++k) { a[2 * k] = av[k][0]; a[2 * k + 1] = av[k][1]; }
    float di = dinv[wid];
    float v[16];
    const float4* bp = (const float4*)b;
#pragma unroll
    for (int kq = 0; kq < 4; ++kq) {
        float4 bv = bp[gl * 4 + kq];
        v[kq * 4 + 0] = fmaf(di, a[kq * 4 + 0], bv.x);
        v[kq * 4 + 1] = fmaf(di, a[kq * 4 + 1], bv.y);
        v[kq * 4 + 2] = fmaf(di, a[kq * 4 + 2], bv.z);
        v[kq * 4 + 3] = fmaf(di, a[kq * 4 + 3], bv.w);
    }
    float m = v[0];
#pragma unroll
    for (int k = 1; k < 16; ++k) m = fmaxf(m, v[k]);
    m = fmaxf(m, __shfl_xor(m, 1));
    m = fmaxf(m, __shfl_xor(m, 2));
    float s = 0.f;
#pragma unroll
    for (int k = 0; k < 16; ++k) s += expf(v[k] - m);
    s += __shfl_xor(s, 1);
    s += __shfl_xor(s, 2);
    float ls = m + logf(s);
#pragma unroll
    for (int kq = 0; kq < 4; ++kq) {
        float4 o4;
        o4.x = v[kq * 4 + 0] - ls;
        o4.y = v[kq * 4 + 1] - ls;
        o4.z = v[kq * 4 + 2] - ls;
        o4.w = v[kq * 4 + 3] - ls;
        ((float4*)OUT)[(size_t)wid * 16 + gl * 4 + kq] = o4;
    }
}

extern "C" void kernel_launch(void* const* d_in, const int* in_sizes, int n_in,
                              void* d_out, int out_size, void* d_ws, size_t ws_size,
                              hipStream_t stream) {
    const float* x = (const float*)d_in[0];
    const int* ei = (const int*)d_in[1];  // [2, NE] int32
    const float* W1 = (const float*)d_in[2];
    const float* b1 = (const float*)d_in[3];
    const float* W2 = (const float*)d_in[4];
    const float* b2 = (const float*)d_in[5];
    float* out = (float*)d_out;

    const int* src = ei;
    const int* dst = ei + NE;

    // workspace layout (all segments 16B-aligned)
    int* pcnt = (int*)d_ws;                                  // NB*NCH ints (153KB)
    uint2* rs2 = (uint2*)(pcnt + NB * NCH + 2);              // NN uint2
    float* dinv = (float*)(rs2 + NN);                        // NN
    unsigned short* Wpk1 = (unsigned short*)(dinv + NN);     // 2048*8 bf16 (32KB)
    unsigned short* Wpk2 = Wpk1 + 2048 * 8;                  // 1024*8 bf16 (16KB)
    unsigned* eord = (unsigned*)(Wpk2 + 1024 * 8);           // NB*NCH*SCAP u32 (12.3MB)
    unsigned short* esrc16 = (unsigned short*)(eord + (size_t)NB * NCH * SCAP);  // NB*ECAP u16
    unsigned* H1f8 = (unsigned*)(esrc16 + (size_t)NB * ECAP);  // (NN+1)*32 u32 (fp8, +sentinel)
    unsigned* H2f8 = H1f8 + (size_t)(NN + 1) * 32;           // (NN+1)*16 u32 (fp8, +sentinel)

    k_scat1<<<NCH + 13, 256, 0, stream>>>(src, dst, pcnt, eord, W1, W2, Wpk1, Wpk2, H1f8, H2f8);
    k_scat2g1<<<NB, 256, 0, stream>>>(pcnt, eord, esrc16, rs2, dinv, x, Wpk1, H1f8);
    k_agg1g2<<<(NN + 31) / 32, 256, 0, stream>>>(rs2, esrc16, H1f8, dinv, b1, Wpk2, H2f8);
    k_agg2_lsm<<<(((NN + 15) / 16) * 64 + 255) / 256, 256, 0, stream>>>(rs2, esrc16, H2f8,
                                                                        dinv, b2, out);
}